// Round 6
// baseline (185.312 us; speedup 1.0000x reference)
//
#include <hip/hip_runtime.h>

#define DD 512
#define NMM 16          // graph blocks (each owns 32 columns of both W's)
#define COLS 32
#define SLICES 16
#define EPSF 1e-12f

typedef float f32x4 __attribute__((ext_vector_type(4)));

// ---------------- pure copy kernel: img -> out+2048 ----------------
// 2048 blocks x 256 threads x 10 f32x4 = 5,242,880 f32x4 exactly.
// Cached loads (img is L3-warm from the harness d_in restore),
// nontemporal stores (dst is write-once, keep it out of L2/L3).
__global__ __launch_bounds__(256) void copy_kernel(
    const float* __restrict__ img, float* __restrict__ out)
{
    const f32x4* __restrict__ src = (const f32x4*)img;
    f32x4* __restrict__ dst = (f32x4*)(out + 4 * DD);
    const long long S = 2048LL * 256;            // 524,288 threads
    const long long t = (long long)blockIdx.x * 256 + threadIdx.x;
    f32x4 v[10];
    #pragma unroll
    for (int j = 0; j < 10; j++) v[j] = src[t + j * S];
    #pragma unroll
    for (int j = 0; j < 10; j++) __builtin_nontemporal_store(v[j], &dst[t + j * S]);
}

// ---------------- graph kernel: 16 blocks x 512 threads ----------------
__global__ __launch_bounds__(512) void graph_kernel(
    const float* __restrict__ bt,   // base_text_features (4,512)
    const float* __restrict__ bi,   // base_img_features  (4,512)
    const float* __restrict__ Wtt,  // (512,512)
    const float* __restrict__ btt,  // (4,512)
    const float* __restrict__ Wit,  // (512,512)
    const float* __restrict__ bit_, // (4,512)
    float* __restrict__ out)
{
    const int bid = blockIdx.x;
    const int tid = threadIdx.x;

    __shared__ float dots[36];      // 0..9 bt pairs, 10..19 bi pairs, 20+b*4+j cross
    __shared__ float coef[4][9];    // per batch: tt[4], it0, it[4]
    __shared__ float u[2][4][DD];   // (m, b, k) folded input vectors
    __shared__ float red[8][SLICES][COLS]; // (m*4+b, slice, col) partials

    // ---- phase 1: 36 dot products ----
    {
        const int pi_[10] = {0,0,0,0,1,1,1,2,2,3};
        const int pj_[10] = {0,1,2,3,1,2,3,2,3,3};
        const int wave = tid >> 6;
        const int lane = tid & 63;
        for (int dotid = wave; dotid < 36; dotid += 8) {
            const float *uu, *vv;
            if (dotid < 10)      { uu = bt + pi_[dotid] * DD;      vv = bt + pj_[dotid] * DD; }
            else if (dotid < 20) { uu = bi + pi_[dotid - 10] * DD; vv = bi + pj_[dotid - 10] * DD; }
            else { int r = dotid - 20; uu = bt + (r >> 2) * DD;    vv = bi + (r & 3) * DD; }
            float s = 0.f;
            #pragma unroll
            for (int e = lane; e < DD; e += 64) s += uu[e] * vv[e];
            #pragma unroll
            for (int off = 32; off; off >>= 1) s += __shfl_xor(s, off, 64);
            if (lane == 0) dots[dotid] = s;
        }
    }
    __syncthreads();

    // ---- phase 2: threads 0..3 compute the 9 coefs for batch b = tid ----
    if (tid < 4) {
        const int b = tid;
        auto pidx = [](int i, int j) -> int {
            if (i > j) { int t = i; i = j; j = t; }
            const int base[4] = {0, 4, 7, 9};
            return base[i] + (j - i);
        };
        float ntn[4], nin[4];
        #pragma unroll
        for (int i = 0; i < 4; i++) ntn[i] = fmaxf(sqrtf(dots[pidx(i, i)]), EPSF);
        #pragma unroll
        for (int i = 0; i < 4; i++) nin[i] = fmaxf(sqrtf(dots[10 + pidx(i, i)]), EPSF);

        // tt graph: nodes = [bt[b], bt[0..3]]
        {
            int map[5] = {b, 0, 1, 2, 3};
            float adj[5][5];
            #pragma unroll
            for (int r = 0; r < 5; r++)
                #pragma unroll
                for (int c = 0; c < 5; c++) {
                    float cv = dots[pidx(map[r], map[c])] / (ntn[map[r]] * ntn[map[c]]);
                    adj[r][c] = fmaxf(cv, 0.f) + (r == c ? 1.f : 0.f);
                }
            float dinv[5];
            #pragma unroll
            for (int r = 0; r < 5; r++) {
                float dd = 0.f;
                #pragma unroll
                for (int c = 0; c < 5; c++) dd += adj[r][c];
                dinv[r] = 1.0f / sqrtf(dd);
            }
            float w[5];
            #pragma unroll
            for (int j = 0; j < 5; j++) w[j] = dinv[0] * adj[0][j] * dinv[j];
            float ct[4] = {w[1], w[2], w[3], w[4]};
            ct[b] += w[0];
            #pragma unroll
            for (int i = 0; i < 4; i++) coef[b][i] = ct[i];
        }
        // it graph: nodes = [bt[b], bi[0..3]]
        {
            float adj[5][5];
            #pragma unroll
            for (int r = 0; r < 5; r++)
                #pragma unroll
                for (int c = 0; c < 5; c++) {
                    float cv;
                    if (r == 0 && c == 0)      cv = dots[pidx(b, b)] / (ntn[b] * ntn[b]);
                    else if (r == 0)           cv = dots[20 + b * 4 + (c - 1)] / (ntn[b] * nin[c - 1]);
                    else if (c == 0)           cv = dots[20 + b * 4 + (r - 1)] / (ntn[b] * nin[r - 1]);
                    else                       cv = dots[10 + pidx(r - 1, c - 1)] / (nin[r - 1] * nin[c - 1]);
                    adj[r][c] = fmaxf(cv, 0.f) + (r == c ? 1.f : 0.f);
                }
            float dinv[5];
            #pragma unroll
            for (int r = 0; r < 5; r++) {
                float dd = 0.f;
                #pragma unroll
                for (int c = 0; c < 5; c++) dd += adj[r][c];
                dinv[r] = 1.0f / sqrtf(dd);
            }
            float w[5];
            #pragma unroll
            for (int j = 0; j < 5; j++) w[j] = dinv[0] * adj[0][j] * dinv[j];
            coef[b][4] = w[0];
            #pragma unroll
            for (int j = 0; j < 4; j++) coef[b][5 + j] = w[j + 1];
        }
    }
    __syncthreads();

    // ---- phase 3: fold coefs into u vectors (thread k = tid) ----
    {
        const int k = tid;
        #pragma unroll
        for (int b = 0; b < 4; b++) {
            float s1 = 0.f;
            #pragma unroll
            for (int i = 0; i < 4; i++) s1 += coef[b][i] * bt[i * DD + k];
            u[0][b][k] = s1;
            float s2 = coef[b][4] * bt[b * DD + k];
            #pragma unroll
            for (int j = 0; j < 4; j++) s2 += coef[b][5 + j] * bi[j * DD + k];
            u[1][b][k] = s2;
        }
    }
    __syncthreads();

    // ---- phase 4: W matmul, k-split across 16 slices, 32 cols/block ----
    {
        const int c  = tid & (COLS - 1);
        const int ks = tid >> 5;            // 0..15
        const int col = bid * COLS + c;
        const int k0 = ks * (DD / SLICES);  // 32 k's per slice
        float acc[2][4] = {};
        const float* __restrict__ Ws[2] = {Wtt, Wit};
        #pragma unroll
        for (int m = 0; m < 2; m++) {
            const float* __restrict__ W = Ws[m];
            #pragma unroll 8
            for (int kk = 0; kk < DD / SLICES; kk++) {
                const int k = k0 + kk;
                const float w = W[k * DD + col];
                #pragma unroll
                for (int b = 0; b < 4; b++) acc[m][b] += u[m][b][k] * w;
            }
        }
        #pragma unroll
        for (int m = 0; m < 2; m++)
            #pragma unroll
            for (int b = 0; b < 4; b++)
                red[m * 4 + b][ks][c] = acc[m][b];
    }
    __syncthreads();

    // ---- phase 5: reduce slices, tanh, blend, write 32 cols × 4 batches ----
    if (tid < 4 * COLS) {
        const int c = tid & (COLS - 1);
        const int b = tid >> 5;
        const int col = bid * COLS + c;
        float stt = 0.f, sit = 0.f;
        #pragma unroll
        for (int s = 0; s < SLICES; s++) {
            stt += red[b][s][c];
            sit += red[4 + b][s][c];
        }
        const float g_tt = tanhf(stt + btt[b * DD + col]);
        const float g_it = tanhf(sit + bit_[b * DD + col]);
        const float go   = 0.7f * g_tt + 0.3f * g_it;          // ALPHA_IT
        out[b * DD + col] = 0.5f * bt[b * DD + col] + 0.5f * go; // BETA_IT
    }
}

extern "C" void kernel_launch(void* const* d_in, const int* in_sizes, int n_in,
                              void* d_out, int out_size, void* d_ws, size_t ws_size,
                              hipStream_t stream) {
    const float* bt   = (const float*)d_in[0];
    const float* bi   = (const float*)d_in[1];
    const float* img  = (const float*)d_in[2];
    const float* Wtt  = (const float*)d_in[3];
    const float* btt  = (const float*)d_in[4];
    const float* Wit  = (const float*)d_in[5];
    const float* bit_ = (const float*)d_in[6];
    float* out = (float*)d_out;

    // Copy first: its store-drain overlaps the graph kernel's execution.
    copy_kernel<<<2048, 256, 0, stream>>>(img, out);
    graph_kernel<<<NMM, 512, 0, stream>>>(bt, bi, Wtt, btt, Wit, bit_, out);
}

// Round 7
// 175.458 us; speedup vs baseline: 1.0562x; 1.0562x over previous
//
#include <hip/hip_runtime.h>

#define DD 512
#define NMM 16          // graph blocks (each owns 32 columns of both W's)
#define COLS 32
#define SLICES 16
#define EPSF 1e-12f

// ---------------- graph kernel: 16 blocks x 512 threads ----------------
__global__ __launch_bounds__(512) void graph_kernel(
    const float* __restrict__ bt,   // base_text_features (4,512)
    const float* __restrict__ bi,   // base_img_features  (4,512)
    const float* __restrict__ Wtt,  // (512,512)
    const float* __restrict__ btt,  // (4,512)
    const float* __restrict__ Wit,  // (512,512)
    const float* __restrict__ bit_, // (4,512)
    float* __restrict__ out)
{
    const int bid = blockIdx.x;
    const int tid = threadIdx.x;

    __shared__ float dots[36];      // 0..9 bt pairs, 10..19 bi pairs, 20+b*4+j cross
    __shared__ float coef[4][9];    // per batch: tt[4], it0, it[4]
    __shared__ float u[2][4][DD];   // (m, b, k) folded input vectors
    __shared__ float red[8][SLICES][COLS]; // (m*4+b, slice, col) partials

    // ---- phase 1: 36 dot products ----
    {
        const int pi_[10] = {0,0,0,0,1,1,1,2,2,3};
        const int pj_[10] = {0,1,2,3,1,2,3,2,3,3};
        const int wave = tid >> 6;
        const int lane = tid & 63;
        for (int dotid = wave; dotid < 36; dotid += 8) {
            const float *uu, *vv;
            if (dotid < 10)      { uu = bt + pi_[dotid] * DD;      vv = bt + pj_[dotid] * DD; }
            else if (dotid < 20) { uu = bi + pi_[dotid - 10] * DD; vv = bi + pj_[dotid - 10] * DD; }
            else { int r = dotid - 20; uu = bt + (r >> 2) * DD;    vv = bi + (r & 3) * DD; }
            float s = 0.f;
            #pragma unroll
            for (int e = lane; e < DD; e += 64) s += uu[e] * vv[e];
            #pragma unroll
            for (int off = 32; off; off >>= 1) s += __shfl_xor(s, off, 64);
            if (lane == 0) dots[dotid] = s;
        }
    }
    __syncthreads();

    // ---- phase 2: threads 0..3 compute the 9 coefs for batch b = tid ----
    if (tid < 4) {
        const int b = tid;
        auto pidx = [](int i, int j) -> int {
            if (i > j) { int t = i; i = j; j = t; }
            const int base[4] = {0, 4, 7, 9};
            return base[i] + (j - i);
        };
        float ntn[4], nin[4];
        #pragma unroll
        for (int i = 0; i < 4; i++) ntn[i] = fmaxf(sqrtf(dots[pidx(i, i)]), EPSF);
        #pragma unroll
        for (int i = 0; i < 4; i++) nin[i] = fmaxf(sqrtf(dots[10 + pidx(i, i)]), EPSF);

        // tt graph: nodes = [bt[b], bt[0..3]]
        {
            int map[5] = {b, 0, 1, 2, 3};
            float adj[5][5];
            #pragma unroll
            for (int r = 0; r < 5; r++)
                #pragma unroll
                for (int c = 0; c < 5; c++) {
                    float cv = dots[pidx(map[r], map[c])] / (ntn[map[r]] * ntn[map[c]]);
                    adj[r][c] = fmaxf(cv, 0.f) + (r == c ? 1.f : 0.f);
                }
            float dinv[5];
            #pragma unroll
            for (int r = 0; r < 5; r++) {
                float dd = 0.f;
                #pragma unroll
                for (int c = 0; c < 5; c++) dd += adj[r][c];
                dinv[r] = 1.0f / sqrtf(dd);
            }
            float w[5];
            #pragma unroll
            for (int j = 0; j < 5; j++) w[j] = dinv[0] * adj[0][j] * dinv[j];
            float ct[4] = {w[1], w[2], w[3], w[4]};
            ct[b] += w[0];
            #pragma unroll
            for (int i = 0; i < 4; i++) coef[b][i] = ct[i];
        }
        // it graph: nodes = [bt[b], bi[0..3]]
        {
            float adj[5][5];
            #pragma unroll
            for (int r = 0; r < 5; r++)
                #pragma unroll
                for (int c = 0; c < 5; c++) {
                    float cv;
                    if (r == 0 && c == 0)      cv = dots[pidx(b, b)] / (ntn[b] * ntn[b]);
                    else if (r == 0)           cv = dots[20 + b * 4 + (c - 1)] / (ntn[b] * nin[c - 1]);
                    else if (c == 0)           cv = dots[20 + b * 4 + (r - 1)] / (ntn[b] * nin[r - 1]);
                    else                       cv = dots[10 + pidx(r - 1, c - 1)] / (nin[r - 1] * nin[c - 1]);
                    adj[r][c] = fmaxf(cv, 0.f) + (r == c ? 1.f : 0.f);
                }
            float dinv[5];
            #pragma unroll
            for (int r = 0; r < 5; r++) {
                float dd = 0.f;
                #pragma unroll
                for (int c = 0; c < 5; c++) dd += adj[r][c];
                dinv[r] = 1.0f / sqrtf(dd);
            }
            float w[5];
            #pragma unroll
            for (int j = 0; j < 5; j++) w[j] = dinv[0] * adj[0][j] * dinv[j];
            coef[b][4] = w[0];
            #pragma unroll
            for (int j = 0; j < 4; j++) coef[b][5 + j] = w[j + 1];
        }
    }
    __syncthreads();

    // ---- phase 3: fold coefs into u vectors (thread k = tid) ----
    {
        const int k = tid;
        #pragma unroll
        for (int b = 0; b < 4; b++) {
            float s1 = 0.f;
            #pragma unroll
            for (int i = 0; i < 4; i++) s1 += coef[b][i] * bt[i * DD + k];
            u[0][b][k] = s1;
            float s2 = coef[b][4] * bt[b * DD + k];
            #pragma unroll
            for (int j = 0; j < 4; j++) s2 += coef[b][5 + j] * bi[j * DD + k];
            u[1][b][k] = s2;
        }
    }
    __syncthreads();

    // ---- phase 4: W matmul, k-split across 16 slices, 32 cols/block ----
    {
        const int c  = tid & (COLS - 1);
        const int ks = tid >> 5;            // 0..15
        const int col = bid * COLS + c;
        const int k0 = ks * (DD / SLICES);  // 32 k's per slice
        float acc[2][4] = {};
        const float* __restrict__ Ws[2] = {Wtt, Wit};
        #pragma unroll
        for (int m = 0; m < 2; m++) {
            const float* __restrict__ W = Ws[m];
            #pragma unroll 8
            for (int kk = 0; kk < DD / SLICES; kk++) {
                const int k = k0 + kk;
                const float w = W[k * DD + col];
                #pragma unroll
                for (int b = 0; b < 4; b++) acc[m][b] += u[m][b][k] * w;
            }
        }
        #pragma unroll
        for (int m = 0; m < 2; m++)
            #pragma unroll
            for (int b = 0; b < 4; b++)
                red[m * 4 + b][ks][c] = acc[m][b];
    }
    __syncthreads();

    // ---- phase 5: reduce slices, tanh, blend, write 32 cols × 4 batches ----
    if (tid < 4 * COLS) {
        const int c = tid & (COLS - 1);
        const int b = tid >> 5;
        const int col = bid * COLS + c;
        float stt = 0.f, sit = 0.f;
        #pragma unroll
        for (int s = 0; s < SLICES; s++) {
            stt += red[b][s][c];
            sit += red[4 + b][s][c];
        }
        const float g_tt = tanhf(stt + btt[b * DD + col]);
        const float g_it = tanhf(sit + bit_[b * DD + col]);
        const float go   = 0.7f * g_tt + 0.3f * g_it;          // ALPHA_IT
        out[b * DD + col] = 0.5f * bt[b * DD + col] + 0.5f * go; // BETA_IT
    }
}

extern "C" void kernel_launch(void* const* d_in, const int* in_sizes, int n_in,
                              void* d_out, int out_size, void* d_ws, size_t ws_size,
                              hipStream_t stream) {
    const float* bt   = (const float*)d_in[0];
    const float* bi   = (const float*)d_in[1];
    const float* img  = (const float*)d_in[2];
    const float* Wtt  = (const float*)d_in[3];
    const float* btt  = (const float*)d_in[4];
    const float* Wit  = (const float*)d_in[5];
    const float* bit_ = (const float*)d_in[6];
    float* out = (float*)d_out;

    // AMD-tuned D2D blit for the bulk pass-through (A/B vs hand copies).
    hipMemcpyAsync(out + 4 * DD, img, 40960ULL * 512 * 4,
                   hipMemcpyDeviceToDevice, stream);
    graph_kernel<<<NMM, 512, 0, stream>>>(bt, bi, Wtt, btt, Wit, bit_, out);
}

// Round 8
// 160.859 us; speedup vs baseline: 1.1520x; 1.0908x over previous
//
#include <hip/hip_runtime.h>

#define DD 512
#define NMM 16          // graph blocks (each owns 32 columns of both W's)
#define COLS 32
#define SLICES 16
#define NCOPY 4096      // copy blocks (512 thr): 4096*512 threads, 2-3 f32x4 each
#define EPSF 1e-12f

typedef float f32x4 __attribute__((ext_vector_type(4)));

__global__ __launch_bounds__(512) void graph_fused(
    const float* __restrict__ bt,   // base_text_features (4,512)
    const float* __restrict__ bi,   // base_img_features  (4,512)
    const float* __restrict__ img,  // img_feature        (40960,512)
    const float* __restrict__ Wtt,  // (512,512)
    const float* __restrict__ btt,  // (4,512)
    const float* __restrict__ Wit,  // (512,512)
    const float* __restrict__ bit_, // (4,512)
    float* __restrict__ out)
{
    const int bid = blockIdx.x;
    const int tid = threadIdx.x;

    if (bid >= NMM) {
        // ---- bulk copy: NT loads + NT stores, fine-grained blocks ----
        // n4 = 40960*512/4 = 5,242,880 f32x4; S = 4096*512 = 2,097,152 threads
        // each thread: elements t, t+S, and (first half only) t+2S
        const f32x4* __restrict__ src = (const f32x4*)img;
        f32x4* __restrict__ dst = (f32x4*)(out + 4 * DD);
        const long long S = (long long)NCOPY * 512;
        const long long n4 = 40960LL * 512 / 4;
        const long long t = (long long)(bid - NMM) * 512 + tid;
        f32x4 v0 = __builtin_nontemporal_load(&src[t]);
        f32x4 v1 = __builtin_nontemporal_load(&src[t + S]);
        __builtin_nontemporal_store(v0, &dst[t]);
        __builtin_nontemporal_store(v1, &dst[t + S]);
        const long long t2 = t + 2 * S;
        if (t2 < n4) {
            f32x4 v2 = __builtin_nontemporal_load(&src[t2]);
            __builtin_nontemporal_store(v2, &dst[t2]);
        }
        return;
    }

    // ======== graph blocks: each redundantly computes dots/coefs/u, ========
    // ======== then does a 32-column chunk of both W matmuls          ========
    __shared__ float dots[36];      // 0..9 bt pairs, 10..19 bi pairs, 20+b*4+j cross
    __shared__ float coef[4][9];    // per batch: tt[4], it0, it[4]
    __shared__ float u[2][4][DD];   // (m, b, k) folded input vectors
    __shared__ float red[8][SLICES][COLS]; // (m*4+b, slice, col) partials

    // ---- phase 1: 36 dot products ----
    {
        const int pi_[10] = {0,0,0,0,1,1,1,2,2,3};
        const int pj_[10] = {0,1,2,3,1,2,3,2,3,3};
        const int wave = tid >> 6;
        const int lane = tid & 63;
        for (int dotid = wave; dotid < 36; dotid += 8) {
            const float *uu, *vv;
            if (dotid < 10)      { uu = bt + pi_[dotid] * DD;      vv = bt + pj_[dotid] * DD; }
            else if (dotid < 20) { uu = bi + pi_[dotid - 10] * DD; vv = bi + pj_[dotid - 10] * DD; }
            else { int r = dotid - 20; uu = bt + (r >> 2) * DD;    vv = bi + (r & 3) * DD; }
            float s = 0.f;
            #pragma unroll
            for (int e = lane; e < DD; e += 64) s += uu[e] * vv[e];
            #pragma unroll
            for (int off = 32; off; off >>= 1) s += __shfl_xor(s, off, 64);
            if (lane == 0) dots[dotid] = s;
        }
    }
    __syncthreads();

    // ---- phase 2: threads 0..3 compute the 9 coefs for batch b = tid ----
    if (tid < 4) {
        const int b = tid;
        auto pidx = [](int i, int j) -> int {
            if (i > j) { int t = i; i = j; j = t; }
            const int base[4] = {0, 4, 7, 9};
            return base[i] + (j - i);
        };
        float ntn[4], nin[4];
        #pragma unroll
        for (int i = 0; i < 4; i++) ntn[i] = fmaxf(sqrtf(dots[pidx(i, i)]), EPSF);
        #pragma unroll
        for (int i = 0; i < 4; i++) nin[i] = fmaxf(sqrtf(dots[10 + pidx(i, i)]), EPSF);

        // tt graph: nodes = [bt[b], bt[0..3]]
        {
            int map[5] = {b, 0, 1, 2, 3};
            float adj[5][5];
            #pragma unroll
            for (int r = 0; r < 5; r++)
                #pragma unroll
                for (int c = 0; c < 5; c++) {
                    float cv = dots[pidx(map[r], map[c])] / (ntn[map[r]] * ntn[map[c]]);
                    adj[r][c] = fmaxf(cv, 0.f) + (r == c ? 1.f : 0.f);
                }
            float dinv[5];
            #pragma unroll
            for (int r = 0; r < 5; r++) {
                float dd = 0.f;
                #pragma unroll
                for (int c = 0; c < 5; c++) dd += adj[r][c];
                dinv[r] = 1.0f / sqrtf(dd);
            }
            float w[5];
            #pragma unroll
            for (int j = 0; j < 5; j++) w[j] = dinv[0] * adj[0][j] * dinv[j];
            float ct[4] = {w[1], w[2], w[3], w[4]};
            ct[b] += w[0];
            #pragma unroll
            for (int i = 0; i < 4; i++) coef[b][i] = ct[i];
        }
        // it graph: nodes = [bt[b], bi[0..3]]
        {
            float adj[5][5];
            #pragma unroll
            for (int r = 0; r < 5; r++)
                #pragma unroll
                for (int c = 0; c < 5; c++) {
                    float cv;
                    if (r == 0 && c == 0)      cv = dots[pidx(b, b)] / (ntn[b] * ntn[b]);
                    else if (r == 0)           cv = dots[20 + b * 4 + (c - 1)] / (ntn[b] * nin[c - 1]);
                    else if (c == 0)           cv = dots[20 + b * 4 + (r - 1)] / (ntn[b] * nin[r - 1]);
                    else                       cv = dots[10 + pidx(r - 1, c - 1)] / (nin[r - 1] * nin[c - 1]);
                    adj[r][c] = fmaxf(cv, 0.f) + (r == c ? 1.f : 0.f);
                }
            float dinv[5];
            #pragma unroll
            for (int r = 0; r < 5; r++) {
                float dd = 0.f;
                #pragma unroll
                for (int c = 0; c < 5; c++) dd += adj[r][c];
                dinv[r] = 1.0f / sqrtf(dd);
            }
            float w[5];
            #pragma unroll
            for (int j = 0; j < 5; j++) w[j] = dinv[0] * adj[0][j] * dinv[j];
            coef[b][4] = w[0];
            #pragma unroll
            for (int j = 0; j < 4; j++) coef[b][5 + j] = w[j + 1];
        }
    }
    __syncthreads();

    // ---- phase 3: fold coefs into u vectors (thread k = tid) ----
    {
        const int k = tid;
        #pragma unroll
        for (int b = 0; b < 4; b++) {
            float s1 = 0.f;
            #pragma unroll
            for (int i = 0; i < 4; i++) s1 += coef[b][i] * bt[i * DD + k];
            u[0][b][k] = s1;
            float s2 = coef[b][4] * bt[b * DD + k];
            #pragma unroll
            for (int j = 0; j < 4; j++) s2 += coef[b][5 + j] * bi[j * DD + k];
            u[1][b][k] = s2;
        }
    }
    __syncthreads();

    // ---- phase 4: W matmul, k-split across 16 slices, 32 cols/block ----
    {
        const int c  = tid & (COLS - 1);
        const int ks = tid >> 5;            // 0..15
        const int col = bid * COLS + c;
        const int k0 = ks * (DD / SLICES);  // 32 k's per slice
        float acc[2][4] = {};
        const float* __restrict__ Ws[2] = {Wtt, Wit};
        #pragma unroll
        for (int m = 0; m < 2; m++) {
            const float* __restrict__ W = Ws[m];
            #pragma unroll 8
            for (int kk = 0; kk < DD / SLICES; kk++) {
                const int k = k0 + kk;
                const float w = W[k * DD + col];
                #pragma unroll
                for (int b = 0; b < 4; b++) acc[m][b] += u[m][b][k] * w;
            }
        }
        #pragma unroll
        for (int m = 0; m < 2; m++)
            #pragma unroll
            for (int b = 0; b < 4; b++)
                red[m * 4 + b][ks][c] = acc[m][b];
    }
    __syncthreads();

    // ---- phase 5: reduce slices, tanh, blend, write 32 cols × 4 batches ----
    if (tid < 4 * COLS) {
        const int c = tid & (COLS - 1);
        const int b = tid >> 5;
        const int col = bid * COLS + c;
        float stt = 0.f, sit = 0.f;
        #pragma unroll
        for (int s = 0; s < SLICES; s++) {
            stt += red[b][s][c];
            sit += red[4 + b][s][c];
        }
        const float g_tt = tanhf(stt + btt[b * DD + col]);
        const float g_it = tanhf(sit + bit_[b * DD + col]);
        const float go   = 0.7f * g_tt + 0.3f * g_it;          // ALPHA_IT
        out[b * DD + col] = 0.5f * bt[b * DD + col] + 0.5f * go; // BETA_IT
    }
}

extern "C" void kernel_launch(void* const* d_in, const int* in_sizes, int n_in,
                              void* d_out, int out_size, void* d_ws, size_t ws_size,
                              hipStream_t stream) {
    const float* bt   = (const float*)d_in[0];
    const float* bi   = (const float*)d_in[1];
    const float* img  = (const float*)d_in[2];
    const float* Wtt  = (const float*)d_in[3];
    const float* btt  = (const float*)d_in[4];
    const float* Wit  = (const float*)d_in[5];
    const float* bit_ = (const float*)d_in[6];
    float* out = (float*)d_out;

    graph_fused<<<NMM + NCOPY, 512, 0, stream>>>(bt, bi, img, Wtt, btt, Wit, bit_, out);
}